// Round 9
// baseline (11258.372 us; speedup 1.0000x reference)
//
#include <hip/hip_runtime.h>

typedef __bf16 bf16;
typedef __bf16 bf16x4 __attribute__((ext_vector_type(4)));
typedef __bf16 bf16x8 __attribute__((ext_vector_type(8)));
typedef float f32x4 __attribute__((ext_vector_type(4)));
typedef unsigned long long u64;
typedef unsigned int u32;

#define T_STEPS 1024
#define BATCH   64
#define DIN     256
#define HID     1024
#define NBLK    64    // 16 feature-quads (64 feat) x 4 batch-groups (16 batch)
#define RING    8     // h ring-buffer depth (slot = t & 7)
#define SENT    0x7F7F7F7Fu   // two bf16 3.39e38 — unreachable by the RNN

// ---------------------------------------------------------------------------
// Kernel 1: xproj[t][b][h] = sum_d x[b][t][d] * w_ih[h][d]   (bf16 out)
// ---------------------------------------------------------------------------
__global__ __launch_bounds__(256) void xproj_gemm(
    const float* __restrict__ x, const float* __restrict__ w_ih,
    bf16* __restrict__ xproj)
{
    __shared__ bf16 As[128 * 40];
    __shared__ bf16 Bs[128 * 40];
    const int tid = threadIdx.x;
    const int m0 = blockIdx.x * 128;
    const int n0 = blockIdx.y * 128;
    const int w = tid >> 6, lane = tid & 63;
    const int r = lane & 15, q = lane >> 4;

    f32x4 acc[2][8];
    #pragma unroll
    for (int i = 0; i < 2; i++)
        #pragma unroll
        for (int j = 0; j < 8; j++)
            acc[i][j] = (f32x4){0.f, 0.f, 0.f, 0.f};

    for (int kk = 0; kk < 8; kk++) {
        const int k0 = kk * 32;
        __syncthreads();
        #pragma unroll
        for (int j = 0; j < 4; j++) {
            int u = tid + j * 256;
            int row = u >> 3, c4 = u & 7;
            float4 fa = *(const float4*)&x[(size_t)(m0 + row) * DIN + k0 + c4 * 4];
            bf16x4 va = { (bf16)fa.x, (bf16)fa.y, (bf16)fa.z, (bf16)fa.w };
            *(bf16x4*)&As[row * 40 + c4 * 4] = va;
            float4 fb = *(const float4*)&w_ih[(size_t)(n0 + row) * DIN + k0 + c4 * 4];
            bf16x4 vb = { (bf16)fb.x, (bf16)fb.y, (bf16)fb.z, (bf16)fb.w };
            *(bf16x4*)&Bs[row * 40 + c4 * 4] = vb;
        }
        __syncthreads();
        bf16x8 a0 = *(const bf16x8*)&As[(w * 32 + r) * 40 + q * 8];
        bf16x8 a1 = *(const bf16x8*)&As[(w * 32 + 16 + r) * 40 + q * 8];
        #pragma unroll
        for (int nt = 0; nt < 8; nt++) {
            bf16x8 bb = *(const bf16x8*)&Bs[(nt * 16 + r) * 40 + q * 8];
            acc[0][nt] = __builtin_amdgcn_mfma_f32_16x16x32_bf16(a0, bb, acc[0][nt], 0, 0, 0);
            acc[1][nt] = __builtin_amdgcn_mfma_f32_16x16x32_bf16(a1, bb, acc[1][nt], 0, 0, 0);
        }
    }

    #pragma unroll
    for (int mi = 0; mi < 2; mi++)
        #pragma unroll
        for (int nt = 0; nt < 8; nt++)
            #pragma unroll
            for (int reg = 0; reg < 4; reg++) {
                int gm = m0 + w * 32 + mi * 16 + q * 4 + reg;   // x row = b*T + t
                int n  = n0 + nt * 16 + r;
                int b  = gm >> 10, t = gm & 1023;
                xproj[(((t << 6) + b) << 10) + n] = (bf16)acc[mi][nt][reg];
            }
}

// ---------------------------------------------------------------------------
// Kernel 2: persistent recurrence, NBLK=64 blocks x 256 thr (4 waves).
// Block (fgq, bg): features fgq*64..+64, batches bg*16..+16.
// Each WAVE is an independent node: 16 features (fgq*64 + w*16 .. +16) x
// 16 batches, FULL K=1024 -> no LDS reduce, NO in-loop __syncthreads.
// 4 independent 64-wave lattices (one per batch-group).
// Self-validating h (SENT sentinel); poll is windowed: 32 x 16-B windows,
// each gated+MFMA'd independently -> late producers overlap with compute.
// u64 agent-scope atomic loads (compiler-tracked waits; no asm hazard).
// W_hh B-fragments fully register-hoisted (128 VGPRs; 1 wave/SIMD budget).
// Ring depth 8; wave re-sentinels its region of slot (t+4)&7 each step.
// ---------------------------------------------------------------------------
__global__ __launch_bounds__(256, 1) void rnn_rec(
    const float* __restrict__ w_hh, const float* __restrict__ b_mod,
    const bf16* __restrict__ xproj, u64* __restrict__ hbuf,
    float* __restrict__ hT)
{
    __shared__ bf16 Wl[64 * 1032];       // 132 KB staging (+8 pad)

    const int tid = threadIdx.x;
    const int fgq = (int)(blockIdx.x >> 2);   // 0..15
    const int bg  = (int)(blockIdx.x & 3);    // 0..3
    const int f0 = fgq * 64;
    const int w = tid >> 6, lane = tid & 63;
    const int r = lane & 15, q = lane >> 4;
    const int myF = f0 + w * 16 + r;          // feature this lane finalizes
    const int batchA = bg * 16 + r;           // A-frag row = batch

    // Stage W rows f0..f0+63 (fp32 -> bf16) into LDS, once.
    for (int j = 0; j < 64; j++) {
        int u = tid + j * 256;                  // float4 units, 0..16383
        int row = u >> 8, c4 = u & 255;
        float4 f = *(const float4*)&w_hh[(size_t)(f0 + row) * HID + c4 * 4];
        bf16x4 v = { (bf16)f.x, (bf16)f.y, (bf16)f.z, (bf16)f.w };
        *(bf16x4*)&Wl[row * 1032 + c4 * 4] = v;
    }
    const float bc = b_mod[myF];
    __syncthreads();

    // Hoist full-K B fragments: 32 windows x 16 B = 128 VGPRs, loop-invariant.
    bf16x8 Bf[32];
    #pragma unroll
    for (int ks = 0; ks < 32; ks++)
        Bf[ks] = *(const bf16x8*)&Wl[(w * 16 + r) * 1032 + ks * 32 + q * 8];

    u32* hbuf32 = (u32*)hbuf;

    // xproj prefetch for t=0
    float xpv[4];
    #pragma unroll
    for (int reg = 0; reg < 4; reg++) {
        int b = bg * 16 + q * 4 + reg;
        xpv[reg] = (float)xproj[(b << 10) + myF];
    }

    for (int t = 0; t < T_STEPS; t++) {
        const int rp = t & (RING - 1), wp = (t + 1) & (RING - 1);
        const u64* H = hbuf + (size_t)rp * 16384 + (size_t)batchA * 256 + q * 2;

        // ---- windowed self-validating poll + incremental MFMA ----
        union { u64 u[2]; u32 wd[4]; bf16x8 f; } A[32];
        f32x4 acc0 = {0.f,0.f,0.f,0.f}, acc1 = {0.f,0.f,0.f,0.f};
        f32x4 acc2 = {0.f,0.f,0.f,0.f}, acc3 = {0.f,0.f,0.f,0.f};
        u32 pend = 0xFFFFFFFFu;
        while (pend) {
            #pragma unroll
            for (int ks = 0; ks < 32; ks++) {
                if (pend & (1u << ks)) {
                    A[ks].u[0] = __hip_atomic_load(&H[ks * 8    ], __ATOMIC_RELAXED, __HIP_MEMORY_SCOPE_AGENT);
                    A[ks].u[1] = __hip_atomic_load(&H[ks * 8 + 1], __ATOMIC_RELAXED, __HIP_MEMORY_SCOPE_AGENT);
                }
            }
            #pragma unroll
            for (int ks = 0; ks < 32; ks++) {
                if (pend & (1u << ks)) {
                    bool ok = (A[ks].wd[0] != SENT) & (A[ks].wd[1] != SENT)
                            & (A[ks].wd[2] != SENT) & (A[ks].wd[3] != SENT);
                    if (__all((int)ok)) {
                        switch (ks & 3) {
                            case 0: acc0 = __builtin_amdgcn_mfma_f32_16x16x32_bf16(A[ks].f, Bf[ks], acc0, 0, 0, 0); break;
                            case 1: acc1 = __builtin_amdgcn_mfma_f32_16x16x32_bf16(A[ks].f, Bf[ks], acc1, 0, 0, 0); break;
                            case 2: acc2 = __builtin_amdgcn_mfma_f32_16x16x32_bf16(A[ks].f, Bf[ks], acc2, 0, 0, 0); break;
                            default: acc3 = __builtin_amdgcn_mfma_f32_16x16x32_bf16(A[ks].f, Bf[ks], acc3, 0, 0, 0); break;
                        }
                        pend &= ~(1u << ks);
                    }
                }
            }
        }

        // ---- finalize my 16x16 tile ----
        f32x4 zs = (acc0 + acc1) + (acc2 + acc3);
        float hv4[4];
        #pragma unroll
        for (int reg = 0; reg < 4; reg++) {
            float z = zs[reg] + xpv[reg];
            hv4[reg] = copysignf(fmaxf(fabsf(z) + bc, 0.0f), z);
        }

        if (t == T_STEPS - 1) {
            #pragma unroll
            for (int reg = 0; reg < 4; reg++)
                hT[myF * 64 + bg * 16 + q * 4 + reg] = hv4[reg];   // fp32 [H][B]
        } else {
            // store h_{t+1} into slot wp (u32-atomic coherent stores)
            #pragma unroll
            for (int reg = 0; reg < 4; reg++) {
                const int b = bg * 16 + q * 4 + reg;
                float other = __shfl_xor(hv4[reg], 1);
                if ((r & 1) == 0) {
                    u32 lo = (u32)__builtin_bit_cast(unsigned short, (bf16)hv4[reg]);
                    u32 hi = (u32)__builtin_bit_cast(unsigned short, (bf16)other);
                    __hip_atomic_store(&hbuf32[(size_t)wp * 32768 + (b << 9) + (myF >> 1)],
                                       lo | (hi << 16), __ATOMIC_RELAXED, __HIP_MEMORY_SCOPE_AGENT);
                }
            }
            // re-sentinel my region of slot (t+4)&7 (readers done: skew <= 1
            // within a batch-group lattice; same-address order + per-step
            // vmcnt waits order sentinel@t before data@t+3)
            const size_t sp = (size_t)((t + 4) & (RING - 1)) * 32768;
            #pragma unroll
            for (int reg = 0; reg < 4; reg++) {
                const int b = bg * 16 + q * 4 + reg;
                if ((r & 1) == 0)
                    __hip_atomic_store(&hbuf32[sp + (b << 9) + (myF >> 1)],
                                       SENT, __ATOMIC_RELAXED, __HIP_MEMORY_SCOPE_AGENT);
            }
            // prefetch next step's xproj (off the critical chain)
            #pragma unroll
            for (int reg = 0; reg < 4; reg++) {
                int b = bg * 16 + q * 4 + reg;
                xpv[reg] = (float)xproj[((size_t)(t + 1) << 16) + (b << 10) + myF];
            }
        }
    }
}

// ---------------------------------------------------------------------------
// Kernel 3: out[b][c] = hT[:,b] . w_fc[c,:] + b_fc[c]   (fp32)
// ---------------------------------------------------------------------------
__global__ __launch_bounds__(256) void fc_head(
    const float* __restrict__ hT, const float* __restrict__ w_fc,
    const float* __restrict__ b_fc, float* __restrict__ out)
{
    const int tid = threadIdx.x;
    const int b = tid & 63;
    const int c = blockIdx.x * 4 + (tid >> 6);
    float acc = b_fc[c];
    #pragma unroll 8
    for (int k = 0; k < HID; k++)
        acc = fmaf(hT[k * 64 + b], w_fc[(size_t)c * HID + k], acc);
    out[b * 1000 + c] = acc;
}

// ---------------------------------------------------------------------------
extern "C" void kernel_launch(void* const* d_in, const int* in_sizes, int n_in,
                              void* d_out, int out_size, void* d_ws, size_t ws_size,
                              hipStream_t stream)
{
    const float* x     = (const float*)d_in[0];
    const float* w_ih  = (const float*)d_in[1];
    const float* w_hh  = (const float*)d_in[2];
    const float* b_mod = (const float*)d_in[3];
    const float* w_fc  = (const float*)d_in[4];
    const float* b_fc  = (const float*)d_in[5];
    float* out = (float*)d_out;

    char* ws = (char*)d_ws;
    // ws layout:
    //   [0, 128 MiB)              xproj bf16  [T][B][H]
    //   [+0, +1 MiB)              hbuf bf16   ring[8][B][H]
    //   [+1 MiB, +1.25 MiB)       hT fp32     [H][B]
    bf16*  xproj = (bf16*)ws;
    u64*   hbuf  = (u64*)(ws + 134217728);
    float* hT    = (float*)(ws + 134217728 + 1048576);

    // ring init: slot 0 = h0 = 0 (valid data), slots 1..7 = sentinel bytes
    hipMemsetAsync(hbuf, 0, 131072, stream);
    hipMemsetAsync((char*)hbuf + 131072, 0x7F, 7 * 131072, stream);

    dim3 g1(512, 8);
    xproj_gemm<<<g1, 256, 0, stream>>>(x, w_ih, xproj);
    rnn_rec<<<NBLK, 256, 0, stream>>>(w_hh, b_mod, xproj, hbuf, hT);
    fc_head<<<250, 256, 0, stream>>>(hT, w_fc, b_fc, out);
}